// Round 2
// baseline (292.414 us; speedup 1.0000x reference)
//
#include <hip/hip_runtime.h>
#include <math.h>

#define B 16
#define S 2048
#define C 1024
#define H 8
#define HD 128

typedef float f32x4 __attribute__((ext_vector_type(4)));  // native vec for nontemporal builtin

// ---------------------------------------------------------------------------
// k1: blocks [0, B*H):   qk[b,h,d] = sum_e (pref[b,h]*Wq[e]+bq[e]) * Wk[e,d]
//     blocks [B*H, +HD): WvT[d][e] = Wv[e][d]   (one-time 64 KiB transpose so
//                        k3's GEMV inner loop is lane-coalesced)
// (the q·bk term is softmax-shift-invariant and dropped)
// ---------------------------------------------------------------------------
__global__ __launch_bounds__(128) void k1_qk_tr(
    const float* __restrict__ pref, const float* __restrict__ Wq,
    const float* __restrict__ bq, const float* __restrict__ Wk,
    const float* __restrict__ Wv, float* __restrict__ qk,
    float* __restrict__ WvT) {
    __shared__ float qsh[HD];
    int blk = blockIdx.x;
    int d   = threadIdx.x;            // 0..127
    if (blk < B * H) {
        float p = pref[blk];
        qsh[d] = p * Wq[d] + bq[d];
        __syncthreads();
        float s = 0.f;
#pragma unroll 8
        for (int e = 0; e < HD; ++e)
            s += qsh[e] * Wk[e * HD + d];      // coalesced across d
        qk[blk * HD + d] = s;
    } else {
        int e = blk - B * H;                   // 0..127: row of Wv
        WvT[d * HD + e] = Wv[e * HD + d];      // coalesced read, scattered write (64 KiB total)
    }
}

// ---------------------------------------------------------------------------
// k2: one streaming pass over features. Per block: one (b, s-chunk) of R rows.
// Thread t (0..255) loads float4 at column 4t -> head h = t>>5.
// Per row: 32-lane butterfly reduce -> score; DEFER-MAX online softmax:
// only rescale (m, l, fbar) when the max grows by >8 (exp(8) ~ 3e3, safe in
// fp32). Common path per row: reduce -> 1 exp -> 5 independent FMAs.
// ---------------------------------------------------------------------------
__global__ __launch_bounds__(256) void k2_pass(
    const float* __restrict__ feat, const float* __restrict__ qk,
    float* __restrict__ pm, float* __restrict__ pl, float* __restrict__ pf,
    int NC, int R) {
    int wg    = blockIdx.x;          // b*NC + chunk
    int b     = wg / NC;
    int chunk = wg - b * NC;
    int t     = threadIdx.x;         // 0..255
    int h     = t >> 5;
    int lane32 = t & 31;

    const float4* frow = (const float4*)feat
                       + (size_t)(b * S + chunk * R) * (C / 4) + t;
    float4 qv = ((const float4*)qk)[(b * H + h) * (HD / 4) + lane32];

    float m = -1e30f, l = 0.f;
    float a0 = 0.f, a1 = 0.f, a2 = 0.f, a3 = 0.f;

    for (int s = 0; s < R; ++s) {
        float4 f = frow[(size_t)s * (C / 4)];
        float part = f.x * qv.x + f.y * qv.y + f.z * qv.z + f.w * qv.w;
        part += __shfl_xor(part, 16, 32);
        part += __shfl_xor(part, 8, 32);
        part += __shfl_xor(part, 4, 32);
        part += __shfl_xor(part, 2, 32);
        part += __shfl_xor(part, 1, 32);     // all 32 lanes hold the score
        // defer-max: rescale only when the running max grew by >8.
        // __any makes the branch wave-uniform (the two 32-lane head-groups
        // in this wave rescale together; each uses its own lane-local max).
        if (__any(part - m > 8.f)) {
            float mn    = fmaxf(m, part);
            float scale = __expf(m - mn);    // exp(-1e30)->0 on first row: ok
            l *= scale; a0 *= scale; a1 *= scale; a2 *= scale; a3 *= scale;
            m = mn;
        }
        float p = __expf(part - m);          // bounded by exp(8)
        l  += p;
        a0 += p * f.x;
        a1 += p * f.y;
        a2 += p * f.z;
        a3 += p * f.w;
    }
    if (lane32 == 0) { pm[wg * H + h] = m; pl[wg * H + h] = l; }
    float4 o; o.x = a0; o.y = a1; o.z = a2; o.w = a3;
    ((float4*)pf)[(size_t)wg * (C / 4) + t] = o;
}

// ---------------------------------------------------------------------------
// k3: per (b,h): combine NC chunk partials -> normalized fbar[128],
// then ctx[b,h,e] = sum_d fbar[d]*WvT[d,e] + bv[e].
// WvT makes the GEMV inner loop coalesced (consecutive lanes -> consecutive
// addresses) instead of 64-distinct-lines-per-load.
// ---------------------------------------------------------------------------
__global__ __launch_bounds__(128) void k3_combine(
    const float* __restrict__ pm, const float* __restrict__ pl,
    const float* __restrict__ pf, const float* __restrict__ WvT,
    const float* __restrict__ bv, float* __restrict__ ctx, int NC) {
    int bh = blockIdx.x;             // b*H + h
    int b = bh >> 3, h = bh & 7;
    int t = threadIdx.x;             // 0..127
    __shared__ float wsh[64];        // NC <= 64
    __shared__ float fsh[HD];

    float M = -1e30f;
    for (int i = 0; i < NC; ++i)
        M = fmaxf(M, pm[(b * NC + i) * H + h]);   // broadcast loads
    if (t < NC) wsh[t] = __expf(pm[(b * NC + t) * H + h] - M);
    __syncthreads();
    float L = 0.f;
    for (int i = 0; i < NC; ++i)
        L += pl[(b * NC + i) * H + h] * wsh[i];
    float acc = 0.f;
    for (int i = 0; i < NC; ++i)
        acc += pf[(size_t)(b * NC + i) * C + h * HD + t] * wsh[i];
    fsh[t] = acc / L;
    __syncthreads();
    float s = 0.f;
#pragma unroll 8
    for (int d = 0; d < HD; ++d)
        s += fsh[d] * WvT[d * HD + t];            // coalesced across t
    ctx[bh * HD + t] = s + bv[t];
}

// ---------------------------------------------------------------------------
// k4: out[b,s,c] = features[b,s,c] + ctx[b,c]   (float4 streaming)
// Nontemporal stores: keep `out` from evicting `features` out of the 256 MiB
// Infinity Cache, so the feat re-read (written hot by k2) stays an L3 hit.
// ---------------------------------------------------------------------------
__global__ __launch_bounds__(256) void k4_epilogue(
    const float* __restrict__ feat, const float* __restrict__ ctx,
    float* __restrict__ out) {
    size_t i = (size_t)blockIdx.x * blockDim.x + threadIdx.x;  // float4 index
    f32x4 f = ((const f32x4*)feat)[i];
    size_t b  = i >> 19;          // / (S*C/4) = 524288
    size_t c4 = i & 255;          // % (C/4)
    f32x4 cv = ((const f32x4*)ctx)[b * (C / 4) + c4];
    f32x4 o = f + cv;
    __builtin_nontemporal_store(o, &((f32x4*)out)[i]);
}

extern "C" void kernel_launch(void* const* d_in, const int* in_sizes, int n_in,
                              void* d_out, int out_size, void* d_ws, size_t ws_size,
                              hipStream_t stream) {
    const float* feat = (const float*)d_in[0];
    const float* pref = (const float*)d_in[1];
    const float* Wq   = (const float*)d_in[2];
    const float* bq   = (const float*)d_in[3];
    const float* Wk   = (const float*)d_in[4];
    // d_in[5] = bk (unused: softmax shift-invariant)
    const float* Wv   = (const float*)d_in[6];
    const float* bv   = (const float*)d_in[7];
    float* out = (float*)d_out;

    // Choose chunks-per-batch NC to fit workspace (prefer 64 for occupancy).
    int NC = 64;
    auto need = [](int nc) {
        return (size_t)(B * H * HD + B * C + HD * HD
                        + 2 * B * nc * H + (size_t)B * nc * C) * 4;
    };
    while (NC > 1 && need(NC) > ws_size) NC >>= 1;
    int R = S / NC;

    float* ws  = (float*)d_ws;
    float* qk  = ws;                  // B*H*HD   = 16384 floats
    float* ctx = qk + B * H * HD;     // B*C      = 16384
    float* WvT = ctx + B * C;         // HD*HD    = 16384
    float* pm  = WvT + HD * HD;       // B*NC*H
    float* pl  = pm + B * NC * H;     // B*NC*H
    float* pf  = pl + B * NC * H;     // B*NC*C

    k1_qk_tr<<<B * H + HD, HD, 0, stream>>>(pref, Wq, bq, Wk, Wv, qk, WvT);
    k2_pass<<<B * NC, 256, 0, stream>>>(feat, qk, pm, pl, pf, NC, R);
    k3_combine<<<B * H, HD, 0, stream>>>(pm, pl, pf, WvT, bv, ctx, NC);
    k4_epilogue<<<(B * S * C / 4) / 256, 256, 0, stream>>>(feat, ctx, out);
}